// Round 2
// baseline (792.779 us; speedup 1.0000x reference)
//
#include <hip/hip_runtime.h>
#include <hip/hip_bf16.h>
#include <math.h>

#define BN_EPS 1e-5f
#define B_  96
#define N_  20
#define D_  2048
#define K_  10
#define M_  (B_*N_)   // 1920
#define R_  (2*D_)    // 4096

// ---------------- kernel 1: knn over N=20 points per batch ----------------
// adj[n][m] = |x_n|^2 + |x_m|^2 - 2 <x_n, x_m>; pick k=10 smallest per row,
// ties -> lowest index (matches lax.top_k). Self-distance is exactly 0 here.
__global__ __launch_bounds__(256) void knn_kernel(const float* __restrict__ x,
                                                  int* __restrict__ nn_idx)
{
  int b = blockIdx.x;
  int t = threadIdx.x;
  int wave = t >> 6, lane = t & 63;
  __shared__ float innr[N_*N_];
  __shared__ float adjl[N_*N_];
  const float* xb = x + (size_t)b * N_ * D_;
  for (int p = wave; p < N_*N_; p += 4) {
    int n = p / N_, m = p % N_;
    const float* xn = xb + n * D_;
    const float* xm = xb + m * D_;
    float s = 0.f;
    for (int d = lane; d < D_; d += 64)
      s = fmaf(xn[d], xm[d], s);
    #pragma unroll
    for (int off = 32; off > 0; off >>= 1)
      s += __shfl_xor(s, off, 64);
    if (lane == 0) innr[p] = s;
  }
  __syncthreads();
  // FIX (round 1 bug): N_*N_ = 400 > 256 threads; loop instead of single guard.
  for (int p = t; p < N_*N_; p += 256) {
    int n = p / N_, m = p % N_;
    adjl[p] = innr[n*N_+n] + innr[m*N_+m] - 2.f * innr[p];
  }
  __syncthreads();
  if (t < N_) {
    int n = t;
    unsigned mask = 0;
    for (int it = 0; it < K_; ++it) {
      float bv = INFINITY; int bi = 0;
      for (int m = 0; m < N_; ++m) {
        if (!((mask >> m) & 1u)) {
          float v = adjl[n*N_+m];
          if (v < bv) { bv = v; bi = m; }
        }
      }
      mask |= 1u << bi;
      nn_idx[(b*N_ + n)*K_ + it] = bi;
    }
  }
}

// ---------------- kernel 2: fused NT SGEMM ----------------
// C[m][r] = sum_d X[m][d] * Wrow(r)[d], r<2048 -> W[r][0:2048] (P half),
// r>=2048 -> W[r-2048][2048:4096] (Q half). 128x128 tile, 8x8 micro, BK=16.
__global__ __launch_bounds__(256) void gemm_nt(const float* __restrict__ A,
                                               const float* __restrict__ W,
                                               float* __restrict__ C)
{
  __shared__ float As[16][132];
  __shared__ float Bs[16][132];
  int t = threadIdx.x;
  int m0 = blockIdx.x * 128;
  int r0 = blockIdx.y * 128;
  const float* Ab = A + (size_t)m0 * D_;
  // all 128 r's of this tile are in the same half of W's columns
  const float* Wb = W + (size_t)(r0 & (D_-1)) * R_ + (size_t)(r0 >> 11) * D_;
  int tx = t & 15;   // r dim
  int ty = t >> 4;   // m dim
  float acc[8][8] = {{0.f}};

  for (int k0 = 0; k0 < D_; k0 += 16) {
    #pragma unroll
    for (int i = 0; i < 2; ++i) {
      int ff = t + i * 256;
      int row = ff >> 2;
      int c4 = (ff & 3) * 4;
      float4 a4 = *(const float4*)(Ab + (size_t)row * D_ + k0 + c4);
      float4 b4 = *(const float4*)(Wb + (size_t)row * R_ + k0 + c4);
      As[c4+0][row] = a4.x; As[c4+1][row] = a4.y;
      As[c4+2][row] = a4.z; As[c4+3][row] = a4.w;
      Bs[c4+0][row] = b4.x; Bs[c4+1][row] = b4.y;
      Bs[c4+2][row] = b4.z; Bs[c4+3][row] = b4.w;
    }
    __syncthreads();
    #pragma unroll
    for (int k = 0; k < 16; ++k) {
      float av[8], bv[8];
      *(float4*)&av[0] = *(const float4*)&As[k][ty*8];
      *(float4*)&av[4] = *(const float4*)&As[k][ty*8+4];
      *(float4*)&bv[0] = *(const float4*)&Bs[k][tx*8];
      *(float4*)&bv[4] = *(const float4*)&Bs[k][tx*8+4];
      #pragma unroll
      for (int im = 0; im < 8; ++im)
        #pragma unroll
        for (int ir = 0; ir < 8; ++ir)
          acc[im][ir] = fmaf(av[im], bv[ir], acc[im][ir]);
    }
    __syncthreads();
  }
  #pragma unroll
  for (int im = 0; im < 8; ++im) {
    float* crow = C + (size_t)(m0 + ty*8 + im) * R_ + r0 + tx*8;
    *(float4*)(crow)     = *(const float4*)&acc[im][0];
    *(float4*)(crow + 4) = *(const float4*)&acc[im][4];
  }
}

// ---------------- kernel 3: BN + ReLU + max over (n, kk) ----------------
// out[b][o] = max_{n,kk} relu((P[b,n,o] + Q[b,j,o] - Q[b,n,o] + bias[o])*inv + shift)
// j = nn_idx[b,n,kk] is uniform across the block -> LDS broadcast, no conflicts.
__global__ __launch_bounds__(256) void epilogue_kernel(
    const float* __restrict__ C, const int* __restrict__ nn_idx,
    const float* __restrict__ conv_b,
    const float* __restrict__ gamma, const float* __restrict__ beta,
    const float* __restrict__ mean, const float* __restrict__ var,
    float* __restrict__ out)
{
  int b = blockIdx.x;
  int t = threadIdx.x;
  int o = blockIdx.y * 256 + t;
  __shared__ float Pl[N_][256];
  __shared__ float Ql[N_][256];
  __shared__ int idxl[N_*K_];
  const float* Cb = C + (size_t)(b * N_) * R_ + o;
  #pragma unroll
  for (int n = 0; n < N_; ++n) {
    Pl[n][t] = Cb[(size_t)n * R_];
    Ql[n][t] = Cb[(size_t)n * R_ + D_];
  }
  if (t < N_*K_) idxl[t] = nn_idx[b * N_ * K_ + t];
  __syncthreads();
  float inv = gamma[o] / sqrtf(var[o] + BN_EPS);
  float shift = fmaf(-mean[o], inv, beta[o]);
  float bias = conv_b[o];
  float best = 0.f;   // relu >= 0, so 0 is the identity for the max
  for (int n = 0; n < N_; ++n) {
    float a = Pl[n][t] - Ql[n][t] + bias;
    #pragma unroll
    for (int kk = 0; kk < K_; ++kk) {
      int j = idxl[n*K_ + kk];
      float v = fmaf(a + Ql[j][t], inv, shift);
      best = fmaxf(best, v);
    }
  }
  out[(size_t)b * D_ + o] = best;
}

extern "C" void kernel_launch(void* const* d_in, const int* in_sizes, int n_in,
                              void* d_out, int out_size, void* d_ws, size_t ws_size,
                              hipStream_t stream)
{
  const float* x      = (const float*)d_in[0];
  const float* conv_w = (const float*)d_in[1];
  const float* conv_b = (const float*)d_in[2];
  const float* gamma  = (const float*)d_in[3];
  const float* beta   = (const float*)d_in[4];
  const float* mean   = (const float*)d_in[5];
  const float* var    = (const float*)d_in[6];
  // d_in[7] = n_neighbor, fixed at 10 in setup_inputs -> compile-time K_

  int*   nn_idx = (int*)d_ws;                          // 19200 ints = 76800 B
  float* C      = (float*)((char*)d_ws + 76800);       // 1920*4096*4 = 31.46 MB

  knn_kernel<<<B_, 256, 0, stream>>>(x, nn_idx);
  gemm_nt<<<dim3(M_/128, R_/128), 256, 0, stream>>>(x, conv_w, C);
  epilogue_kernel<<<dim3(B_, D_/256), 256, 0, stream>>>(
      C, nn_idx, conv_b, gamma, beta, mean, var, (float*)d_out);
}

// Round 4
// 150.534 us; speedup vs baseline: 5.2665x; 5.2665x over previous
//
#include <hip/hip_runtime.h>
#include <hip/hip_bf16.h>
#include <math.h>

#define BN_EPS 1e-5f
#define B_  96
#define N_  20
#define D_  2048
#define K_  10
#define M_  (B_*N_)   // 1920
#define R_  (2*D_)    // 4096

typedef __attribute__((ext_vector_type(8))) short bf16x8;
typedef __attribute__((ext_vector_type(4))) float f32x4;
typedef __attribute__((ext_vector_type(8))) unsigned short ushort8;

static __device__ __forceinline__ unsigned short f2bf(float f) {
  unsigned int u = __builtin_bit_cast(unsigned int, f);
  u = u + 0x7fffu + ((u >> 16) & 1u);   // RNE (finite inputs only)
  return (unsigned short)(u >> 16);
}

#define GLOAD_LDS16(g, l) \
  __builtin_amdgcn_global_load_lds((const __attribute__((address_space(1))) void*)(g), \
                                   (__attribute__((address_space(3))) void*)(l), 16, 0, 0)

// ---------------- kernel 1: knn (fp32, float4 loads, 8 waves) ----------------
__global__ __launch_bounds__(512) void knn_kernel(const float* __restrict__ x,
                                                  int* __restrict__ nn_idx)
{
  int b = blockIdx.x, t = threadIdx.x, w = t >> 6, lane = t & 63;
  __shared__ float innr[N_*N_];
  __shared__ float adjl[N_*N_];
  const float* xb = x + (size_t)b * N_ * D_;
  for (int p = w; p < N_*N_; p += 8) {
    int n = p / N_, m = p % N_;
    const float4* xn = (const float4*)(xb + n * D_);
    const float4* xm = (const float4*)(xb + m * D_);
    float s = 0.f;
    #pragma unroll
    for (int c = lane; c < D_/4; c += 64) {
      float4 a = xn[c], v = xm[c];
      s = fmaf(a.x, v.x, fmaf(a.y, v.y, fmaf(a.z, v.z, fmaf(a.w, v.w, s))));
    }
    #pragma unroll
    for (int off = 32; off > 0; off >>= 1)
      s += __shfl_xor(s, off, 64);
    if (lane == 0) innr[p] = s;
  }
  __syncthreads();
  for (int p = t; p < N_*N_; p += 512) {
    int n = p / N_, m = p % N_;
    adjl[p] = innr[n*N_+n] + innr[m*N_+m] - 2.f * innr[p];
  }
  __syncthreads();
  if (t < N_) {
    int n = t;
    unsigned mask = 0;
    for (int it = 0; it < K_; ++it) {
      float bv = INFINITY; int bi = 0;
      for (int m = 0; m < N_; ++m) {
        if (!((mask >> m) & 1u)) {
          float v = adjl[n*N_+m];
          if (v < bv) { bv = v; bi = m; }
        }
      }
      mask |= 1u << bi;
      nn_idx[(b*N_ + n)*K_ + it] = bi;
    }
  }
}

// ---------------- kernel 2a: cast x -> bf16 ----------------
__global__ __launch_bounds__(256) void cast_x_kernel(const float* __restrict__ x,
                                                     unsigned short* __restrict__ Xb)
{
  int i = blockIdx.x * 256 + threadIdx.x;          // chunk of 8 elements
  const float4* src = (const float4*)x + (size_t)i * 2;
  float4 a = src[0], c = src[1];
  ushort8 o = { f2bf(a.x), f2bf(a.y), f2bf(a.z), f2bf(a.w),
                f2bf(c.x), f2bf(c.y), f2bf(c.z), f2bf(c.w) };
  *((ushort8*)Xb + i) = o;
}

// ---------------- kernel 2b: cast + repack conv_w -> Wn bf16 ----------------
// Wn[r][k], r=2*o+h: h=0 -> conv_w[o][k] (P/W1), h=1 -> conv_w[o][2048+k] (Q/W2)
__global__ __launch_bounds__(256) void cast_w_kernel(const float* __restrict__ cw,
                                                     unsigned short* __restrict__ Wn)
{
  int i = blockIdx.x * 256 + threadIdx.x;          // chunk of 8 elements of Wn
  int r = i >> 8;                                   // 2048/8 = 256 chunks/row
  int k = (i & 255) * 8;
  const float* src = cw + (size_t)(r >> 1) * R_ + ((r & 1) << 11) + k;
  float4 a = *(const float4*)src, c = *(const float4*)(src + 4);
  ushort8 o = { f2bf(a.x), f2bf(a.y), f2bf(a.z), f2bf(a.w),
                f2bf(c.x), f2bf(c.y), f2bf(c.z), f2bf(c.w) };
  *((ushort8*)Wn + i) = o;
}

// ---------------- kernel 3: fused bf16 MFMA GEMM + BN/ReLU/neighbor-max ----
// Tile: 160 rows (8 batches) x 128 cols (64 outputs, P/Q interleaved), BK=64.
// 8 waves as 2(M)x4(R); wave tile 80x16x2 -> 5x2 frags of 16x16x32 bf16 MFMA.
// Epilogue: acc -> LDS (two 4-batch phases), per-(b,o) max over (n,kk).
__global__ __launch_bounds__(512, 4) void fused_gemm(
    const unsigned short* __restrict__ Xb, const unsigned short* __restrict__ Wn,
    const int* __restrict__ nn_idx, const float* __restrict__ conv_b,
    const float* __restrict__ gamma, const float* __restrict__ beta,
    const float* __restrict__ mean, const float* __restrict__ var,
    float* __restrict__ out)
{
  __shared__ __align__(16) char smem[47360];
  unsigned short* As = (unsigned short*)smem;             // [160][64] bf16, 20480 B
  unsigned short* Bs = (unsigned short*)(smem + 20480);   // [128][64] bf16, 16384 B
  float* Cl  = (float*)smem;                              // [80][128] f32, 40960 B (reuses stage)
  int*   idxl = (int*)(smem + 40960);                     // [8][200] int, 6400 B (disjoint)

  int t = threadIdx.x, lane = t & 63, w = t >> 6;
  int wm = w >> 2, wr = w & 3;
  int m0 = blockIdx.x * 160, b0 = blockIdx.x * 8;
  int r0 = blockIdx.y * 128, o0 = blockIdx.y * 64;
  int rowsel = lane & 15, ksel = lane >> 4;

  for (int i = t; i < 8*N_*K_; i += 512) idxl[i] = nn_idx[b0*N_*K_ + i];

  f32x4 acc[5][2] = {};

  for (int k0 = 0; k0 < D_; k0 += 64) {
    #pragma unroll
    for (int i = 0; i < 3; ++i) {                 // A: 160*8 = 1280 16B-chunks
      int fb = i*512 + (w << 6);
      if (fb < 1280) {
        int flat = fb + lane;
        int row = flat >> 3, kc = flat & 7;
        GLOAD_LDS16(Xb + (size_t)(m0 + row) * D_ + k0 + kc*8, As + flat*8);
      }
    }
    #pragma unroll
    for (int i = 0; i < 2; ++i) {                 // B: 128*8 = 1024 16B-chunks
      int flat = i*512 + t;
      int row = flat >> 3, kc = flat & 7;
      GLOAD_LDS16(Wn + (size_t)(r0 + row) * D_ + k0 + kc*8, Bs + flat*8);
    }
    __syncthreads();
    #pragma unroll
    for (int ks = 0; ks < 2; ++ks) {
      bf16x8 a[5], bfr[2];
      #pragma unroll
      for (int mi = 0; mi < 5; ++mi)
        a[mi] = *(const bf16x8*)(As + (wm*80 + mi*16 + rowsel)*64 + ks*32 + ksel*8);
      #pragma unroll
      for (int ri = 0; ri < 2; ++ri)
        bfr[ri] = *(const bf16x8*)(Bs + (wr*32 + ri*16 + rowsel)*64 + ks*32 + ksel*8);
      #pragma unroll
      for (int mi = 0; mi < 5; ++mi)
        #pragma unroll
        for (int ri = 0; ri < 2; ++ri)
          acc[mi][ri] = __builtin_amdgcn_mfma_f32_16x16x32_bf16(a[mi], bfr[ri], acc[mi][ri], 0, 0, 0);
    }
    __syncthreads();
  }

  // ---- fused epilogue ----
  int pair = (w << 5) | (lane & 31);   // 0..255 -> (bb, oo)
  int half = lane >> 5;                // n-range split, combined via shfl_xor 32
  int bb = pair >> 6, oo = pair & 63;
  int og = o0 + oo;
  float invv  = gamma[og] / sqrtf(var[og] + BN_EPS);
  float shift = fmaf(-mean[og], invv, beta[og]);
  float bias  = conv_b[og];

  #pragma unroll
  for (int phase = 0; phase < 2; ++phase) {
    if (wm == phase) {
      #pragma unroll
      for (int mi = 0; mi < 5; ++mi)
        #pragma unroll
        for (int ri = 0; ri < 2; ++ri)
          #pragma unroll
          for (int rg = 0; rg < 4; ++rg)
            Cl[(mi*16 + ksel*4 + rg)*128 + wr*32 + ri*16 + rowsel] = acc[mi][ri][rg];
    }
    __syncthreads();
    float best = 0.f;                   // relu identity
    int rbase = bb * N_;
    for (int n = half*10; n < half*10 + 10; ++n) {
      float Pv = Cl[(rbase + n)*128 + oo*2];
      float Qn = Cl[(rbase + n)*128 + oo*2 + 1];
      float aa = Pv - Qn + bias;
      const int* ix = idxl + (phase*4 + bb)*N_*K_ + n*K_;
      #pragma unroll
      for (int kk = 0; kk < K_; ++kk) {
        int j = ix[kk];
        float v = fmaf(aa + Cl[(rbase + j)*128 + oo*2 + 1], invv, shift);
        best = fmaxf(best, v);
      }
    }
    best = fmaxf(best, __shfl_xor(best, 32, 64));
    if (half == 0) out[(size_t)(b0 + phase*4 + bb) * D_ + og] = best;
    __syncthreads();
  }
}

extern "C" void kernel_launch(void* const* d_in, const int* in_sizes, int n_in,
                              void* d_out, int out_size, void* d_ws, size_t ws_size,
                              hipStream_t stream)
{
  const float* x      = (const float*)d_in[0];
  const float* conv_w = (const float*)d_in[1];
  const float* conv_b = (const float*)d_in[2];
  const float* gamma  = (const float*)d_in[3];
  const float* beta   = (const float*)d_in[4];
  const float* mean   = (const float*)d_in[5];
  const float* var    = (const float*)d_in[6];

  // workspace: nn_idx 76800 B | Xb bf16 7864320 B | Wn bf16 16777216 B  (24.7 MB)
  int* nn_idx = (int*)d_ws;
  unsigned short* Xb = (unsigned short*)((char*)d_ws + 76800);
  unsigned short* Wn = (unsigned short*)((char*)d_ws + 76800 + (size_t)M_*D_*2);

  knn_kernel<<<B_, 512, 0, stream>>>(x, nn_idx);
  cast_x_kernel<<<(M_*D_/8)/256, 256, 0, stream>>>(x, Xb);
  cast_w_kernel<<<(R_*D_/8)/256, 256, 0, stream>>>(conv_w, Wn);
  fused_gemm<<<dim3(M_/160, R_/128), 512, 0, stream>>>(
      Xb, Wn, nn_idx, conv_b, gamma, beta, mean, var, (float*)d_out);
}

// Round 6
// 92.890 us; speedup vs baseline: 8.5346x; 1.6206x over previous
//
#include <hip/hip_runtime.h>
#include <hip/hip_bf16.h>
#include <math.h>

#define BN_EPS 1e-5f
#define B_  96
#define N_  20
#define D_  2048
#define K_  10
#define M_  (B_*N_)   // 1920
#define R_  (2*D_)    // 4096

typedef __attribute__((ext_vector_type(8))) short bf16x8;
typedef __attribute__((ext_vector_type(4))) float f32x4;
typedef __attribute__((ext_vector_type(8))) unsigned short ushort8;

static __device__ __forceinline__ unsigned short f2bf(float f) {
  unsigned int u = __builtin_bit_cast(unsigned int, f);
  u = u + 0x7fffu + ((u >> 16) & 1u);   // RNE (finite inputs only)
  return (unsigned short)(u >> 16);
}

#define GLOAD_LDS16(g, l) \
  __builtin_amdgcn_global_load_lds((const __attribute__((address_space(1))) void*)(g), \
                                   (__attribute__((address_space(3))) void*)(l), 16, 0, 0)

// ------- kernel 1: knn (fp32, symmetric pairs) + fused cast x->bf16 -------
// 210 unordered pairs (n<=m) instead of 400; innr mirrored into LDS.
__global__ __launch_bounds__(512) void knn_cast_kernel(const float* __restrict__ x,
                                                       int* __restrict__ nn_idx,
                                                       unsigned short* __restrict__ Xb)
{
  int b = blockIdx.x, t = threadIdx.x, w = t >> 6, lane = t & 63;
  __shared__ float innr[N_*N_];
  __shared__ float adjl[N_*N_];
  const float* xb = x + (size_t)b * N_ * D_;
  for (int p = w; p < (N_*(N_+1))/2; p += 8) {   // 210 pairs
    // triangular decode: n = first row with base(n+1) > p
    int n = 0;
    while ((n+1)*N_ - ((n+1)*n)/2 <= p) ++n;
    int m = n + (p - (n*N_ - (n*(n-1))/2));
    const float4* xn = (const float4*)(xb + n * D_);
    const float4* xm = (const float4*)(xb + m * D_);
    float s = 0.f;
    #pragma unroll
    for (int c = lane; c < D_/4; c += 64) {
      float4 a = xn[c], v = xm[c];
      s = fmaf(a.x, v.x, fmaf(a.y, v.y, fmaf(a.z, v.z, fmaf(a.w, v.w, s))));
    }
    #pragma unroll
    for (int off = 32; off > 0; off >>= 1)
      s += __shfl_xor(s, off, 64);
    if (lane == 0) { innr[n*N_+m] = s; innr[m*N_+n] = s; }
  }
  __syncthreads();
  for (int p = t; p < N_*N_; p += 512) {
    int n = p / N_, m = p % N_;
    adjl[p] = innr[n*N_+n] + innr[m*N_+m] - 2.f * innr[p];
  }
  __syncthreads();
  if (t < N_) {
    int n = t;
    unsigned mask = 0;
    for (int it = 0; it < K_; ++it) {
      float bv = INFINITY; int bi = 0;
      for (int m = 0; m < N_; ++m) {
        if (!((mask >> m) & 1u)) {
          float v = adjl[n*N_+m];
          if (v < bv) { bv = v; bi = m; }
        }
      }
      mask |= 1u << bi;
      nn_idx[(b*N_ + n)*K_ + it] = bi;
    }
  }
  // fused cast of this batch's x slice -> bf16 (saves a separate kernel + re-read)
  unsigned short* xo = Xb + (size_t)b * N_ * D_;
  for (int i = t; i < N_*D_/8; i += 512) {
    const float4* src = (const float4*)xb + (size_t)i * 2;
    float4 a = src[0], c = src[1];
    ushort8 o = { f2bf(a.x), f2bf(a.y), f2bf(a.z), f2bf(a.w),
                  f2bf(c.x), f2bf(c.y), f2bf(c.z), f2bf(c.w) };
    *((ushort8*)xo + i) = o;
  }
}

// ---------------- kernel 2: cast + repack conv_w -> Wn bf16 ----------------
// Wn[r][k], r=2*o+h: h=0 -> conv_w[o][k] (P/W1), h=1 -> conv_w[o][2048+k] (Q/W2)
__global__ __launch_bounds__(256) void cast_w_kernel(const float* __restrict__ cw,
                                                     unsigned short* __restrict__ Wn)
{
  int i = blockIdx.x * 256 + threadIdx.x;          // chunk of 8 elements of Wn
  int r = i >> 8;                                   // 2048/8 = 256 chunks/row
  int k = (i & 255) * 8;
  const float* src = cw + (size_t)(r >> 1) * R_ + ((r & 1) << 11) + k;
  float4 a = *(const float4*)src, c = *(const float4*)(src + 4);
  ushort8 o = { f2bf(a.x), f2bf(a.y), f2bf(a.z), f2bf(a.w),
                f2bf(c.x), f2bf(c.y), f2bf(c.z), f2bf(c.w) };
  *((ushort8*)Wn + i) = o;
}

// ---------------- kernel 3: fused bf16 MFMA GEMM + BN/ReLU/neighbor-max ----
// Tile: 80 rows (4 batches) x 128 cols (64 outputs, P/Q interleaved), BK=64.
// 4 waves (1M x 4R); wave tile 80x32 -> 5x2 frags of 16x16x32 bf16 MFMA.
// Grid 24x32 = 768 blocks = exactly 3/CU. Chunk-XOR LDS swizzle (16 -> 8 lanes
// per bank-group): linear gload_lds dest + swizzled GLOBAL source chunk + same
// XOR on ds_read (both-sides-or-neither, rule #21).
__global__ __launch_bounds__(256, 4) void fused_gemm(
    const unsigned short* __restrict__ Xb, const unsigned short* __restrict__ Wn,
    const int* __restrict__ nn_idx, const float* __restrict__ conv_b,
    const float* __restrict__ gamma, const float* __restrict__ beta,
    const float* __restrict__ mean, const float* __restrict__ var,
    float* __restrict__ out)
{
  __shared__ __align__(16) char smem[44160];
  unsigned short* As = (unsigned short*)smem;             // [80][64] bf16, 10240 B
  unsigned short* Bs = (unsigned short*)(smem + 10240);   // [128][64] bf16, 16384 B (ends 26624)
  float* Cl  = (float*)smem;                              // [80][128] f32, 40960 B (reuses stage)
  int*   idxl = (int*)(smem + 40960);                     // [4][200] int, 3200 B (disjoint)

  // bijective XCD-chunk swizzle (768 % 8 == 0): XCD c owns 4 consecutive W-panels
  int flat = blockIdx.y * 24 + blockIdx.x;
  int nf = (flat & 7) * 96 + (flat >> 3);
  int bx = nf % 24, by = nf / 24;

  int t = threadIdx.x, lane = t & 63, w = t >> 6;  // w = wr (0..3)
  int m0 = bx * 80, b0 = bx * 4;
  int r0 = by * 128, o0 = by * 64;
  int rowsel = lane & 15, ksel = lane >> 4;

  for (int i = t; i < 4*N_*K_; i += 256) idxl[i] = nn_idx[b0*N_*K_ + i];

  f32x4 acc[5][2] = {};

  for (int k0 = 0; k0 < D_; k0 += 64) {
    #pragma unroll
    for (int i = 0; i < 3; ++i) {                 // A: 80*8 = 640 16B-chunks
      int fl = i*256 + t;
      if (fl < 640) {
        int row = fl >> 3, kc = fl & 7;
        GLOAD_LDS16(Xb + (size_t)(m0 + row) * D_ + k0 + ((kc ^ (row & 7)) << 3),
                    As + fl*8);
      }
    }
    #pragma unroll
    for (int i = 0; i < 4; ++i) {                 // B: 128*8 = 1024 16B-chunks
      int fl = i*256 + t;
      int row = fl >> 3, kc = fl & 7;
      GLOAD_LDS16(Wn + (size_t)(r0 + row) * D_ + k0 + ((kc ^ (row & 7)) << 3),
                  Bs + fl*8);
    }
    __syncthreads();
    #pragma unroll
    for (int ks = 0; ks < 2; ++ks) {
      int swz = ((ks*4 + ksel) ^ (rowsel & 7)) << 3;   // tile offsets are 16-multiples
      bf16x8 a[5], bfr[2];
      #pragma unroll
      for (int mi = 0; mi < 5; ++mi)
        a[mi] = *(const bf16x8*)(As + (mi*16 + rowsel)*64 + swz);
      #pragma unroll
      for (int ri = 0; ri < 2; ++ri)
        bfr[ri] = *(const bf16x8*)(Bs + (w*32 + ri*16 + rowsel)*64 + swz);
      #pragma unroll
      for (int mi = 0; mi < 5; ++mi)
        #pragma unroll
        for (int ri = 0; ri < 2; ++ri)
          acc[mi][ri] = __builtin_amdgcn_mfma_f32_16x16x32_bf16(a[mi], bfr[ri], acc[mi][ri], 0, 0, 0);
    }
    __syncthreads();
  }

  // ---- fused epilogue ----
  #pragma unroll
  for (int mi = 0; mi < 5; ++mi)
    #pragma unroll
    for (int ri = 0; ri < 2; ++ri)
      #pragma unroll
      for (int rg = 0; rg < 4; ++rg)
        Cl[(mi*16 + ksel*4 + rg)*128 + w*32 + ri*16 + rowsel] = acc[mi][ri][rg];
  __syncthreads();

  int bb = w, oo = lane;               // (batch-in-tile, output-in-tile)
  int og = o0 + oo;
  float invv  = gamma[og] / sqrtf(var[og] + BN_EPS);
  float shift = fmaf(-mean[og], invv, beta[og]);
  float bias  = conv_b[og];
  float best = 0.f;                    // relu identity
  int rbase = bb * N_;
  for (int n = 0; n < N_; ++n) {
    float Pv = Cl[(rbase + n)*128 + oo*2];
    float Qn = Cl[(rbase + n)*128 + oo*2 + 1];
    float aa = Pv - Qn + bias;
    const int* ix = idxl + bb*N_*K_ + n*K_;
    #pragma unroll
    for (int kk = 0; kk < K_; ++kk) {
      int j = ix[kk];
      float v = fmaf(aa + Cl[(rbase + j)*128 + oo*2 + 1], invv, shift);
      best = fmaxf(best, v);
    }
  }
  out[(size_t)(b0 + bb) * D_ + og] = best;
}

extern "C" void kernel_launch(void* const* d_in, const int* in_sizes, int n_in,
                              void* d_out, int out_size, void* d_ws, size_t ws_size,
                              hipStream_t stream)
{
  const float* x      = (const float*)d_in[0];
  const float* conv_w = (const float*)d_in[1];
  const float* conv_b = (const float*)d_in[2];
  const float* gamma  = (const float*)d_in[3];
  const float* beta   = (const float*)d_in[4];
  const float* mean   = (const float*)d_in[5];
  const float* var    = (const float*)d_in[6];

  // workspace: nn_idx 76800 B | Xb bf16 7864320 B | Wn bf16 16777216 B  (24.7 MB)
  int* nn_idx = (int*)d_ws;
  unsigned short* Xb = (unsigned short*)((char*)d_ws + 76800);
  unsigned short* Wn = (unsigned short*)((char*)d_ws + 76800 + (size_t)M_*D_*2);

  knn_cast_kernel<<<B_, 512, 0, stream>>>(x, nn_idx, Xb);
  cast_w_kernel<<<(R_*D_/8)/256, 256, 0, stream>>>(conv_w, Wn);
  fused_gemm<<<dim3(24, 32), 256, 0, stream>>>(
      Xb, Wn, nn_idx, conv_b, gamma, beta, mean, var, (float*)d_out);
}